// Round 1
// baseline (8789.738 us; speedup 1.0000x reference)
//
#include <hip/hip_runtime.h>
#include <math.h>

typedef float f32x4 __attribute__((ext_vector_type(4)));

#define T_    2048
#define DM_   2048
#define KV_   1024
#define L2T_  0.4152410118609203f     // log2(10000)/32

// ---------------------------------------------------------------------------
// Naive f32 QKV GEMM: C = A(4096x2048) @ B(2048x3072). cols<2048 -> qy (f32,
// stride 2048), cols>=2048 -> kv (f32, stride 1024). 64x64 tile, 4x4/thread.
// ---------------------------------------------------------------------------
__global__ __launch_bounds__(256) void qkv_gemm_naive(
    const float* __restrict__ A, const float* __restrict__ B,
    float* __restrict__ Cq, float* __restrict__ Ckv, int M, int N, int K){
  __shared__ float As[64 * 20];
  __shared__ float Bs[16 * 68];
  const int tid = threadIdx.x, tx = tid & 15, ty = tid >> 4;
  const int m0 = blockIdx.y * 64, n0 = blockIdx.x * 64;
  const int ar = tid >> 2, ac = (tid & 3) * 4;
  const int br = tid >> 4, bc = (tid & 15) * 4;

  float acc[4][4];
#pragma unroll
  for (int i = 0; i < 4; ++i)
#pragma unroll
    for (int j = 0; j < 4; ++j) acc[i][j] = 0.f;

  for (int kb = 0; kb < K; kb += 16){
    __syncthreads();
    *(f32x4*)&As[ar * 20 + ac] = *(const f32x4*)&A[(size_t)(m0 + ar) * K + kb + ac];
    *(f32x4*)&Bs[br * 68 + bc] = *(const f32x4*)&B[(size_t)(kb + br) * N + n0 + bc];
    __syncthreads();
#pragma unroll
    for (int kk = 0; kk < 16; ++kk){
      const f32x4 bv = *(const f32x4*)&Bs[kk * 68 + tx * 4];
#pragma unroll
      for (int i = 0; i < 4; ++i){
        const float av = As[(ty * 4 + i) * 20 + kk];
#pragma unroll
        for (int j = 0; j < 4; ++j) acc[i][j] += av * bv[j];
      }
    }
  }

#pragma unroll
  for (int i = 0; i < 4; ++i)
#pragma unroll
    for (int j = 0; j < 4; ++j){
      const int m = m0 + ty * 4 + i, n = n0 + tx * 4 + j;
      if (n < DM_) Cq[(size_t)m * DM_ + n] = acc[i][j];
      else         Ckv[(size_t)m * KV_ + (n - DM_)] = acc[i][j];
    }
}

// ---------------------------------------------------------------------------
// Naive f32 proj GEMM: out(f32) = Y(4096x2048 f32) @ W(2048x2048 f32).
// ---------------------------------------------------------------------------
__global__ __launch_bounds__(256) void proj_gemm_naive(
    const float* __restrict__ A, const float* __restrict__ B,
    float* __restrict__ C, int M, int N, int K){
  __shared__ float As[64 * 20];
  __shared__ float Bs[16 * 68];
  const int tid = threadIdx.x, tx = tid & 15, ty = tid >> 4;
  const int m0 = blockIdx.y * 64, n0 = blockIdx.x * 64;
  const int ar = tid >> 2, ac = (tid & 3) * 4;
  const int br = tid >> 4, bc = (tid & 15) * 4;

  float acc[4][4];
#pragma unroll
  for (int i = 0; i < 4; ++i)
#pragma unroll
    for (int j = 0; j < 4; ++j) acc[i][j] = 0.f;

  for (int kb = 0; kb < K; kb += 16){
    __syncthreads();
    *(f32x4*)&As[ar * 20 + ac] = *(const f32x4*)&A[(size_t)(m0 + ar) * K + kb + ac];
    *(f32x4*)&Bs[br * 68 + bc] = *(const f32x4*)&B[(size_t)(kb + br) * N + n0 + bc];
    __syncthreads();
#pragma unroll
    for (int kk = 0; kk < 16; ++kk){
      const f32x4 bv = *(const f32x4*)&Bs[kk * 68 + tx * 4];
#pragma unroll
      for (int i = 0; i < 4; ++i){
        const float av = As[(ty * 4 + i) * 20 + kk];
#pragma unroll
        for (int j = 0; j < 4; ++j) acc[i][j] += av * bv[j];
      }
    }
  }

#pragma unroll
  for (int i = 0; i < 4; ++i)
#pragma unroll
    for (int j = 0; j < 4; ++j){
      const int m = m0 + ty * 4 + i, n = n0 + tx * 4 + j;
      C[(size_t)m * N + n] = acc[i][j];
    }
}

// ---------------------------------------------------------------------------
// f32 RoPE in place: q (32 heads, fold 1/8 scale) and k (8 groups).
// One block per row (b*T+t); 1280 pairs, 5 per thread.
// ---------------------------------------------------------------------------
__global__ __launch_bounds__(256) void rope_qk_f32(
    float* __restrict__ qm, float* __restrict__ kvm){
  const int row = blockIdx.x;
  const int t = row & (T_ - 1);
#pragma unroll
  for (int it = 0; it < 5; ++it){
    const int p = threadIdx.x + it * 256;
    const int i = p & 31;
    float sv, cv;
    sincosf((float)t * exp2f(-(float)i * L2T_), &sv, &cv);
    float* ptr; float scale;
    if (p < 1024){ ptr = qm + (size_t)row * DM_ + (p >> 5) * 64 + 2 * i; scale = 0.125f; }
    else { ptr = kvm + (size_t)row * KV_ + ((p - 1024) >> 5) * 64 + 2 * i; scale = 1.f; }
    const float a = ptr[0], b = ptr[1];
    ptr[0] = (a * cv - b * sv) * scale;
    ptr[1] = (a * sv + b * cv) * scale;
  }
}

// ---------------------------------------------------------------------------
// Flash-style tiled attention, f32 vector FMA.
// Block = (b, h, 64-query tile), 256 threads (4 waves).
//   - Q tile staged to LDS once, then pulled into 64 VGPRs/thread (4 rows).
//   - Per 64-key tile: stage K,V row-major in LDS; S = Q@K^T with a 4x4
//     micro-tile (keys mapped 16j+tx so K row-start banks stride by 4 =>
//     conflict-free b128 reads); online softmax with shfl_xor butterflies
//     across the 16 lanes of a row group (no LDS reductions, no barriers);
//     P goes to LDS (reusing the Q tile) -- producer and consumer lanes are
//     in the SAME wave, and the DS pipe is in-order per wave, so no barrier.
//   - O columns mapped 4tx+j so PV reads Vs as conflict-free b128 and the
//     final store is a coalesced f32x4.
// 2 barriers per key tile. LDS = 3*64*68*4 = 51 KiB -> 3 blocks/CU.
// q is pre-scaled by 1/8 in RoPE; output written in place over q.
// Reverse q-tile order so heavy (long-causal) blocks are dispatched first.
// ---------------------------------------------------------------------------
#define FS 68

__global__ __launch_bounds__(256, 3) void attn_flash_f32(
    float* __restrict__ qy, const float* __restrict__ kv){
  __shared__ float Qs[64 * FS];   // Q tile; reused as P after q -> regs
  __shared__ float Ks[64 * FS];
  __shared__ float Vs[64 * FS];
  const int tid = threadIdx.x;
  const int tx = tid & 15, ty = tid >> 4;
  const int qt = (int)gridDim.x - 1 - (int)blockIdx.x;
  const int h = blockIdx.y, b = blockIdx.z;
  const int g = h >> 2;
  const int q0 = qt * 64;
  const float* kbase = kv + (size_t)b * T_ * KV_ + g * 64;
  const float* vbase = kbase + 512;
  float* qbase = qy + ((size_t)b * T_ + q0) * DM_ + h * 64;

  // stage Q tile (coalesced), then this thread's 4 rows -> registers
#pragma unroll
  for (int it = 0; it < 4; ++it){
    const int p = tid + it * 256;
    const int r = p >> 4, c = (p & 15) * 4;
    *(f32x4*)&Qs[r * FS + c] = *(const f32x4*)(qbase + (size_t)r * DM_ + c);
  }
  __syncthreads();
  f32x4 qreg[4][16];
#pragma unroll
  for (int i = 0; i < 4; ++i)
#pragma unroll
    for (int c = 0; c < 16; ++c)
      qreg[i][c] = *(const f32x4*)&Qs[(4 * ty + i) * FS + c * 4];

  float m_run[4], l_run[4];
  f32x4 oacc[4];
#pragma unroll
  for (int i = 0; i < 4; ++i){
    m_run[i] = -INFINITY;
    l_run[i] = 0.f;
    oacc[i] = (f32x4){0.f, 0.f, 0.f, 0.f};
  }

  for (int kt = 0; kt <= qt; ++kt){
    __syncthreads();   // all waves done with previous Ks/Vs
#pragma unroll
    for (int it = 0; it < 4; ++it){
      const int p = tid + it * 256;
      const int r = p >> 4, c = (p & 15) * 4;
      const size_t grow = (size_t)(kt * 64 + r) * KV_;
      *(f32x4*)&Ks[r * FS + c] = *(const f32x4*)(kbase + grow + c);
      *(f32x4*)&Vs[r * FS + c] = *(const f32x4*)(vbase + grow + c);
    }
    __syncthreads();

    // S = Q @ K^T ; thread owns rows 4ty+i, keys 16j+tx
    float s[4][4];
#pragma unroll
    for (int i = 0; i < 4; ++i)
#pragma unroll
      for (int j = 0; j < 4; ++j) s[i][j] = 0.f;

#pragma unroll
    for (int c = 0; c < 16; ++c){
      const f32x4 k0 = *(const f32x4*)&Ks[(tx     ) * FS + c * 4];
      const f32x4 k1 = *(const f32x4*)&Ks[(tx + 16) * FS + c * 4];
      const f32x4 k2 = *(const f32x4*)&Ks[(tx + 32) * FS + c * 4];
      const f32x4 k3 = *(const f32x4*)&Ks[(tx + 48) * FS + c * 4];
#pragma unroll
      for (int i = 0; i < 4; ++i){
        const f32x4 q = qreg[i][c];
        s[i][0] += q[0]*k0[0] + q[1]*k0[1] + q[2]*k0[2] + q[3]*k0[3];
        s[i][1] += q[0]*k1[0] + q[1]*k1[1] + q[2]*k1[2] + q[3]*k1[3];
        s[i][2] += q[0]*k2[0] + q[1]*k2[1] + q[2]*k2[2] + q[3]*k2[3];
        s[i][3] += q[0]*k3[0] + q[1]*k3[1] + q[2]*k3[2] + q[3]*k3[3];
      }
    }

    // causal mask: only the diagonal tile needs it
    if (kt == qt){
#pragma unroll
      for (int i = 0; i < 4; ++i)
#pragma unroll
        for (int j = 0; j < 4; ++j)
          if (16 * j + tx > 4 * ty + i) s[i][j] = -1e30f;
    }

    // online softmax; row spread over 16 lanes (tx), butterfly-reduce
#pragma unroll
    for (int i = 0; i < 4; ++i){
      float t = fmaxf(fmaxf(s[i][0], s[i][1]), fmaxf(s[i][2], s[i][3]));
      t = fmaxf(t, __shfl_xor(t, 1));
      t = fmaxf(t, __shfl_xor(t, 2));
      t = fmaxf(t, __shfl_xor(t, 4));
      t = fmaxf(t, __shfl_xor(t, 8));
      const float mnew = fmaxf(m_run[i], t);
      const float corr = __expf(m_run[i] - mnew);
      float rs = 0.f;
#pragma unroll
      for (int j = 0; j < 4; ++j){
        const float p = __expf(s[i][j] - mnew);
        s[i][j] = p;
        rs += p;
      }
      rs += __shfl_xor(rs, 1);
      rs += __shfl_xor(rs, 2);
      rs += __shfl_xor(rs, 4);
      rs += __shfl_xor(rs, 8);
      m_run[i] = mnew;
      l_run[i] = l_run[i] * corr + rs;
      oacc[i] *= corr;
#pragma unroll
      for (int j = 0; j < 4; ++j)
        Qs[(4 * ty + i) * FS + 16 * j + tx] = s[i][j];   // P tile (own wave's rows)
    }

    // O += P @ V  (P rows 4ty+i live in this wave; DS pipe in-order -> no barrier)
#pragma unroll 8
    for (int kk = 0; kk < 64; ++kk){
      const f32x4 vq = *(const f32x4*)&Vs[kk * FS + tx * 4];
#pragma unroll
      for (int i = 0; i < 4; ++i){
        const float pw = Qs[(4 * ty + i) * FS + kk];
        oacc[i] += pw * vq;
      }
    }
  }

#pragma unroll
  for (int i = 0; i < 4; ++i){
    const float inv = 1.f / l_run[i];
    const f32x4 r = oacc[i] * inv;
    *(f32x4*)(qbase + (size_t)(4 * ty + i) * DM_ + tx * 4) = r;
  }
}

// ---------------------------------------------------------------------------
extern "C" void kernel_launch(void* const* d_in, const int* in_sizes, int n_in,
                              void* d_out, int out_size, void* d_ws, size_t ws_size,
                              hipStream_t stream) {
  // Select inputs by element count (robust to ordering).
  const float *x = nullptr, *w_qkv = nullptr, *w_proj = nullptr;
  for (int i = 0; i < n_in; ++i){
    if (in_sizes[i] == 8388608)      x      = (const float*)d_in[i];
    else if (in_sizes[i] == 6291456) w_qkv  = (const float*)d_in[i];
    else if (in_sizes[i] == 4194304) w_proj = (const float*)d_in[i];
  }
  float* out = (float*)d_out;   // reference output dtype is float32

  // ws (50.3 MB): qy f32 @0 (33.5MB) ; kv f32 @33.5MB (16.8MB)
  char* ws = (char*)d_ws;
  float* qy  = (float*)ws;
  float* kvb = (float*)(ws + (size_t)33554432);

  qkv_gemm_naive<<<dim3(48, 64), 256, 0, stream>>>(x, w_qkv, qy, kvb, 4096, 3072, 2048);
  rope_qk_f32<<<4096, 256, 0, stream>>>(qy, kvb);
  attn_flash_f32<<<dim3(32, 32, 2), 256, 0, stream>>>(qy, kvb);
  proj_gemm_naive<<<dim3(32, 64), 256, 0, stream>>>(qy, w_proj, out, 4096, 2048, 2048);
}

// Round 2
// 6056.564 us; speedup vs baseline: 1.4513x; 1.4513x over previous
//
#include <hip/hip_runtime.h>
#include <math.h>

typedef float f32x4 __attribute__((ext_vector_type(4)));

#define T_    2048
#define DM_   2048
#define KV_   1024
#define L2T_  0.4152410118609203f     // log2(10000)/32

// ---------------------------------------------------------------------------
// Naive f32 QKV GEMM: C = A(4096x2048) @ B(2048x3072). cols<2048 -> qy (f32,
// stride 2048), cols>=2048 -> kv (f32, stride 1024). 64x64 tile, 4x4/thread.
// ---------------------------------------------------------------------------
__global__ __launch_bounds__(256) void qkv_gemm_naive(
    const float* __restrict__ A, const float* __restrict__ B,
    float* __restrict__ Cq, float* __restrict__ Ckv, int M, int N, int K){
  __shared__ float As[64 * 20];
  __shared__ float Bs[16 * 68];
  const int tid = threadIdx.x, tx = tid & 15, ty = tid >> 4;
  const int m0 = blockIdx.y * 64, n0 = blockIdx.x * 64;
  const int ar = tid >> 2, ac = (tid & 3) * 4;
  const int br = tid >> 4, bc = (tid & 15) * 4;

  float acc[4][4];
#pragma unroll
  for (int i = 0; i < 4; ++i)
#pragma unroll
    for (int j = 0; j < 4; ++j) acc[i][j] = 0.f;

  for (int kb = 0; kb < K; kb += 16){
    __syncthreads();
    *(f32x4*)&As[ar * 20 + ac] = *(const f32x4*)&A[(size_t)(m0 + ar) * K + kb + ac];
    *(f32x4*)&Bs[br * 68 + bc] = *(const f32x4*)&B[(size_t)(kb + br) * N + n0 + bc];
    __syncthreads();
#pragma unroll
    for (int kk = 0; kk < 16; ++kk){
      const f32x4 bv = *(const f32x4*)&Bs[kk * 68 + tx * 4];
#pragma unroll
      for (int i = 0; i < 4; ++i){
        const float av = As[(ty * 4 + i) * 20 + kk];
#pragma unroll
        for (int j = 0; j < 4; ++j) acc[i][j] += av * bv[j];
      }
    }
  }

#pragma unroll
  for (int i = 0; i < 4; ++i)
#pragma unroll
    for (int j = 0; j < 4; ++j){
      const int m = m0 + ty * 4 + i, n = n0 + tx * 4 + j;
      if (n < DM_) Cq[(size_t)m * DM_ + n] = acc[i][j];
      else         Ckv[(size_t)m * KV_ + (n - DM_)] = acc[i][j];
    }
}

// ---------------------------------------------------------------------------
// Naive f32 proj GEMM: out(f32) = Y(4096x2048 f32) @ W(2048x2048 f32).
// ---------------------------------------------------------------------------
__global__ __launch_bounds__(256) void proj_gemm_naive(
    const float* __restrict__ A, const float* __restrict__ B,
    float* __restrict__ C, int M, int N, int K){
  __shared__ float As[64 * 20];
  __shared__ float Bs[16 * 68];
  const int tid = threadIdx.x, tx = tid & 15, ty = tid >> 4;
  const int m0 = blockIdx.y * 64, n0 = blockIdx.x * 64;
  const int ar = tid >> 2, ac = (tid & 3) * 4;
  const int br = tid >> 4, bc = (tid & 15) * 4;

  float acc[4][4];
#pragma unroll
  for (int i = 0; i < 4; ++i)
#pragma unroll
    for (int j = 0; j < 4; ++j) acc[i][j] = 0.f;

  for (int kb = 0; kb < K; kb += 16){
    __syncthreads();
    *(f32x4*)&As[ar * 20 + ac] = *(const f32x4*)&A[(size_t)(m0 + ar) * K + kb + ac];
    *(f32x4*)&Bs[br * 68 + bc] = *(const f32x4*)&B[(size_t)(kb + br) * N + n0 + bc];
    __syncthreads();
#pragma unroll
    for (int kk = 0; kk < 16; ++kk){
      const f32x4 bv = *(const f32x4*)&Bs[kk * 68 + tx * 4];
#pragma unroll
      for (int i = 0; i < 4; ++i){
        const float av = As[(ty * 4 + i) * 20 + kk];
#pragma unroll
        for (int j = 0; j < 4; ++j) acc[i][j] += av * bv[j];
      }
    }
  }

#pragma unroll
  for (int i = 0; i < 4; ++i)
#pragma unroll
    for (int j = 0; j < 4; ++j){
      const int m = m0 + ty * 4 + i, n = n0 + tx * 4 + j;
      C[(size_t)m * N + n] = acc[i][j];
    }
}

// ---------------------------------------------------------------------------
// f32 RoPE in place: q (32 heads, fold 1/8 scale) and k (8 groups).
// One block per row (b*T+t); 1280 pairs, 5 per thread.
// ---------------------------------------------------------------------------
__global__ __launch_bounds__(256) void rope_qk_f32(
    float* __restrict__ qm, float* __restrict__ kvm){
  const int row = blockIdx.x;
  const int t = row & (T_ - 1);
#pragma unroll
  for (int it = 0; it < 5; ++it){
    const int p = threadIdx.x + it * 256;
    const int i = p & 31;
    float sv, cv;
    sincosf((float)t * exp2f(-(float)i * L2T_), &sv, &cv);
    float* ptr; float scale;
    if (p < 1024){ ptr = qm + (size_t)row * DM_ + (p >> 5) * 64 + 2 * i; scale = 0.125f; }
    else { ptr = kvm + (size_t)row * KV_ + ((p - 1024) >> 5) * 64 + 2 * i; scale = 1.f; }
    const float a = ptr[0], b = ptr[1];
    ptr[0] = (a * cv - b * sv) * scale;
    ptr[1] = (a * sv + b * cv) * scale;
  }
}

// ---------------------------------------------------------------------------
// Flash-style tiled attention, f32 vector FMA. v2: NO big register arrays
// (v1's qreg[4][16] spilled to scratch -> 19 GB of HBM traffic).
//   - Q tile lives in LDS for the whole block (QK^T reads it as 4-address
//     broadcasts -- near-free on the DS pipe).
//   - P tile reuses the K buffer (K is dead once S is in registers); one
//     extra barrier between "all waves done reading K" and the P write.
//   - P write / PV read are same-wave (rows 4ty+i owned by ty's wave), and
//     the DS pipe is in-order per wave -> no barrier between them.
//   - All LDS patterns <=2-way bank aliasing (free) at stride 68.
// 3 barriers per 64-key tile. LDS = 3*64*68*4 = 51 KiB -> 3 blocks/CU.
// q pre-scaled by 1/8 in RoPE; output written in place over q.
// Reversed q-tile order so heavy (long-causal) blocks launch first.
// ---------------------------------------------------------------------------
#define FS 68

__global__ __launch_bounds__(256, 3) void attn_flash_f32(
    float* __restrict__ qy, const float* __restrict__ kv){
  __shared__ float Qs[64 * FS];
  __shared__ float Ks[64 * FS];   // K tile; reused as P tile after S
  __shared__ float Vs[64 * FS];
  const int tid = threadIdx.x;
  const int tx = tid & 15, ty = tid >> 4;
  const int qt = (int)gridDim.x - 1 - (int)blockIdx.x;
  const int h = blockIdx.y, b = blockIdx.z;
  const int g = h >> 2;
  const float* kbase = kv + (size_t)b * T_ * KV_ + g * 64;
  const float* vbase = kbase + 512;
  float* qbase = qy + ((size_t)b * T_ + qt * 64) * DM_ + h * 64;

  // stage Q tile once (coalesced); visible after first loop barrier
#pragma unroll
  for (int it = 0; it < 4; ++it){
    const int p = tid + it * 256;
    const int r = p >> 4, c = (p & 15) * 4;
    *(f32x4*)&Qs[r * FS + c] = *(const f32x4*)(qbase + (size_t)r * DM_ + c);
  }

  float m_run[4], l_run[4];
  f32x4 oacc[4];
#pragma unroll
  for (int i = 0; i < 4; ++i){
    m_run[i] = -INFINITY;
    l_run[i] = 0.f;
    oacc[i] = (f32x4){0.f, 0.f, 0.f, 0.f};
  }

  for (int kt = 0; kt <= qt; ++kt){
    __syncthreads();   // prev tile fully consumed (and Q staged, 1st iter)
#pragma unroll
    for (int it = 0; it < 4; ++it){
      const int p = tid + it * 256;
      const int r = p >> 4, c = (p & 15) * 4;
      const size_t grow = (size_t)(kt * 64 + r) * KV_;
      *(f32x4*)&Ks[r * FS + c] = *(const f32x4*)(kbase + grow + c);
      *(f32x4*)&Vs[r * FS + c] = *(const f32x4*)(vbase + grow + c);
    }
    __syncthreads();

    // S = Q @ K^T ; thread owns q-rows 4ty+i, keys 16j+tx
    float s[4][4];
#pragma unroll
    for (int i = 0; i < 4; ++i)
#pragma unroll
      for (int j = 0; j < 4; ++j) s[i][j] = 0.f;

#pragma unroll
    for (int c = 0; c < 16; ++c){
      const f32x4 k0 = *(const f32x4*)&Ks[(tx     ) * FS + c * 4];
      const f32x4 k1 = *(const f32x4*)&Ks[(tx + 16) * FS + c * 4];
      const f32x4 k2 = *(const f32x4*)&Ks[(tx + 32) * FS + c * 4];
      const f32x4 k3 = *(const f32x4*)&Ks[(tx + 48) * FS + c * 4];
#pragma unroll
      for (int i = 0; i < 4; ++i){
        const f32x4 q = *(const f32x4*)&Qs[(4 * ty + i) * FS + c * 4];
        s[i][0] += q[0]*k0[0] + q[1]*k0[1] + q[2]*k0[2] + q[3]*k0[3];
        s[i][1] += q[0]*k1[0] + q[1]*k1[1] + q[2]*k1[2] + q[3]*k1[3];
        s[i][2] += q[0]*k2[0] + q[1]*k2[1] + q[2]*k2[2] + q[3]*k2[3];
        s[i][3] += q[0]*k3[0] + q[1]*k3[1] + q[2]*k3[2] + q[3]*k3[3];
      }
    }

    // causal mask: only the diagonal tile needs it
    if (kt == qt){
#pragma unroll
      for (int i = 0; i < 4; ++i)
#pragma unroll
        for (int j = 0; j < 4; ++j)
          if (16 * j + tx > 4 * ty + i) s[i][j] = -1e30f;
    }

    // online softmax in regs; row spread over 16 tx-lanes, butterfly-reduce
#pragma unroll
    for (int i = 0; i < 4; ++i){
      float t = fmaxf(fmaxf(s[i][0], s[i][1]), fmaxf(s[i][2], s[i][3]));
      t = fmaxf(t, __shfl_xor(t, 1));
      t = fmaxf(t, __shfl_xor(t, 2));
      t = fmaxf(t, __shfl_xor(t, 4));
      t = fmaxf(t, __shfl_xor(t, 8));
      const float mnew = fmaxf(m_run[i], t);
      const float corr = __expf(m_run[i] - mnew);
      float rs = 0.f;
#pragma unroll
      for (int j = 0; j < 4; ++j){
        const float p = __expf(s[i][j] - mnew);
        s[i][j] = p;
        rs += p;
      }
      rs += __shfl_xor(rs, 1);
      rs += __shfl_xor(rs, 2);
      rs += __shfl_xor(rs, 4);
      rs += __shfl_xor(rs, 8);
      m_run[i] = mnew;
      l_run[i] = l_run[i] * corr + rs;
      oacc[i] *= corr;
    }

    __syncthreads();   // all waves done READING Ks -> safe to overwrite w/ P

#pragma unroll
    for (int i = 0; i < 4; ++i)
#pragma unroll
      for (int j = 0; j < 4; ++j)
        Ks[(4 * ty + i) * FS + 16 * j + tx] = s[i][j];

    // O += P @ V  (P rows 4ty+i written by this wave; DS in-order per wave)
#pragma unroll
    for (int kkb = 0; kkb < 16; ++kkb){
      f32x4 pr[4];
#pragma unroll
      for (int i = 0; i < 4; ++i)
        pr[i] = *(const f32x4*)&Ks[(4 * ty + i) * FS + kkb * 4];
#pragma unroll
      for (int u = 0; u < 4; ++u){
        const f32x4 vq = *(const f32x4*)&Vs[(kkb * 4 + u) * FS + tx * 4];
#pragma unroll
        for (int i = 0; i < 4; ++i)
          oacc[i] += pr[i][u] * vq;
      }
    }
  }

#pragma unroll
  for (int i = 0; i < 4; ++i){
    const float inv = 1.f / l_run[i];
    const f32x4 r = oacc[i] * inv;
    *(f32x4*)(qbase + (size_t)(4 * ty + i) * DM_ + tx * 4) = r;
  }
}

// ---------------------------------------------------------------------------
extern "C" void kernel_launch(void* const* d_in, const int* in_sizes, int n_in,
                              void* d_out, int out_size, void* d_ws, size_t ws_size,
                              hipStream_t stream) {
  // Select inputs by element count (robust to ordering).
  const float *x = nullptr, *w_qkv = nullptr, *w_proj = nullptr;
  for (int i = 0; i < n_in; ++i){
    if (in_sizes[i] == 8388608)      x      = (const float*)d_in[i];
    else if (in_sizes[i] == 6291456) w_qkv  = (const float*)d_in[i];
    else if (in_sizes[i] == 4194304) w_proj = (const float*)d_in[i];
  }
  float* out = (float*)d_out;   // reference output dtype is float32

  // ws (50.3 MB): qy f32 @0 (33.5MB) ; kv f32 @33.5MB (16.8MB)
  char* ws = (char*)d_ws;
  float* qy  = (float*)ws;
  float* kvb = (float*)(ws + (size_t)33554432);

  qkv_gemm_naive<<<dim3(48, 64), 256, 0, stream>>>(x, w_qkv, qy, kvb, 4096, 3072, 2048);
  rope_qk_f32<<<4096, 256, 0, stream>>>(qy, kvb);
  attn_flash_f32<<<dim3(32, 32, 2), 256, 0, stream>>>(qy, kvb);
  proj_gemm_naive<<<dim3(32, 64), 256, 0, stream>>>(qy, w_proj, out, 4096, 2048, 2048);
}